// Round 2
// baseline (1304.022 us; speedup 1.0000x reference)
//
#include <hip/hip_runtime.h>

typedef unsigned short u16;
typedef unsigned int u32;
typedef __attribute__((ext_vector_type(8))) short bf16x8;
typedef __attribute__((ext_vector_type(4))) float f32x4;
typedef __attribute__((ext_vector_type(8))) unsigned short u16x8;
typedef __attribute__((ext_vector_type(4))) unsigned short u16x4;
typedef const __attribute__((address_space(1))) void gvoid;
typedef __attribute__((address_space(3))) void svoid;

#define T_TOK 100352
#define CDIM 256

__device__ __forceinline__ u16 f2bf(float f) {
    u32 u = __float_as_uint(f);
    u32 r = (u + 0x7fffu + ((u >> 16) & 1u)) >> 16;
    return (u16)r;
}
__device__ __forceinline__ float bf2f(u16 h) {
    return __uint_as_float(((u32)h) << 16);
}
__device__ __forceinline__ float gelu_f(float x) {
    return 0.5f * x * (1.0f + erff(x * 0.70710678118654752f));
}
__device__ __forceinline__ int div7(int q) { return (q * 37) >> 8; }  // exact for 0..48

// ---------------- fp32 -> bf16 weight conversion ----------------
__global__ void cvt_kernel(const float* __restrict__ in, u16* __restrict__ out, int n) {
    int i = blockIdx.x * 256 + threadIdx.x;
    if (i < n) out[i] = f2bf(in[i]);
}

// ---------------- LayerNorm (fp32 in, bf16 out) ----------------
__global__ __launch_bounds__(256) void ln_kernel(
    const float* __restrict__ X, const float* __restrict__ w,
    const float* __restrict__ b, u16* __restrict__ Y)
{
    int wid = threadIdx.x >> 6, l = threadIdx.x & 63;
    int t = blockIdx.x * 4 + wid;
    const float4 x4 = ((const float4*)(X + (size_t)t * CDIM))[l];
    float s  = x4.x + x4.y + x4.z + x4.w;
    float s2 = x4.x*x4.x + x4.y*x4.y + x4.z*x4.z + x4.w*x4.w;
    #pragma unroll
    for (int o = 32; o; o >>= 1) { s += __shfl_xor(s, o); s2 += __shfl_xor(s2, o); }
    float mean = s * (1.0f/256.0f);
    float var  = s2 * (1.0f/256.0f) - mean*mean;
    float rstd = rsqrtf(var + 1e-5f);
    float4 w4 = ((const float4*)w)[l];
    float4 b4 = ((const float4*)b)[l];
    ushort4 o4;
    o4.x = f2bf((x4.x - mean)*rstd*w4.x + b4.x);
    o4.y = f2bf((x4.y - mean)*rstd*w4.y + b4.y);
    o4.z = f2bf((x4.z - mean)*rstd*w4.z + b4.z);
    o4.w = f2bf((x4.w - mean)*rstd*w4.w + b4.w);
    ((ushort4*)(Y + (size_t)t * CDIM))[l] = o4;
}

// ---------------- bf16 MFMA GEMM:  out[M,N] = A[M,K] @ B[N,K]^T + bias ----------------
template<int EPI>
__global__ __launch_bounds__(256) void gemm_kernel(
    const u16* __restrict__ A, const u16* __restrict__ Bw,
    const float* __restrict__ bias, void* __restrict__ outp,
    const float* __restrict__ res, int N, int K)
{
    __shared__ u16 lsA[128 * 32];
    __shared__ u16 lsB[128 * 32];
    const int l = threadIdx.x & 63;
    const int w = threadIdx.x >> 6;
    const int mT = blockIdx.y, nT = blockIdx.x;
    const int wr = w >> 1, wc = w & 1;

    f32x4 acc[4][4];
    #pragma unroll
    for (int m = 0; m < 4; ++m)
        #pragma unroll
        for (int n = 0; n < 4; ++n) acc[m][n] = (f32x4){0.f,0.f,0.f,0.f};

    const int rsub = l >> 2;
    const int ksub = (l & 3) * 8;

    for (int kt = 0; kt < K; kt += 32) {
        __syncthreads();
        #pragma unroll
        for (int i = 0; i < 2; ++i) {
            int row = i*64 + w*16 + rsub;
            const u16* ga = A  + (size_t)(mT*128 + row) * K + kt + ksub;
            const u16* gb = Bw + (size_t)(nT*128 + row) * K + kt + ksub;
            u16* la = lsA + i*2048 + w*512;
            u16* lb = lsB + i*2048 + w*512;
            __builtin_amdgcn_global_load_lds((gvoid*)ga, (svoid*)la, 16, 0, 0);
            __builtin_amdgcn_global_load_lds((gvoid*)gb, (svoid*)lb, 16, 0, 0);
        }
        __syncthreads();
        const int lr = l & 15;
        const int lk = (l >> 4) * 8;
        bf16x8 a[4], b[4];
        #pragma unroll
        for (int m = 0; m < 4; ++m) a[m] = *(const bf16x8*)&lsA[(wr*64 + m*16 + lr)*32 + lk];
        #pragma unroll
        for (int n = 0; n < 4; ++n) b[n] = *(const bf16x8*)&lsB[(wc*64 + n*16 + lr)*32 + lk];
        #pragma unroll
        for (int m = 0; m < 4; ++m)
            #pragma unroll
            for (int n = 0; n < 4; ++n)
                acc[m][n] = __builtin_amdgcn_mfma_f32_16x16x32_bf16(a[m], b[n], acc[m][n], 0, 0, 0);
    }

    const int lr4 = (l >> 4) * 4;
    const int lcn = l & 15;
    #pragma unroll
    for (int m = 0; m < 4; ++m) {
        #pragma unroll
        for (int n = 0; n < 4; ++n) {
            int row0 = mT*128 + wr*64 + m*16 + lr4;
            int col  = nT*128 + wc*64 + n*16 + lcn;
            float bb = bias[col];
            #pragma unroll
            for (int j = 0; j < 4; ++j) {
                size_t idx = (size_t)(row0 + j) * N + col;
                float v = acc[m][n][j] + bb;
                if (EPI == 0)      ((u16*)outp)[idx] = f2bf(v);
                else if (EPI == 1) ((u16*)outp)[idx] = f2bf(gelu_f(v));
                else               ((float*)outp)[idx] = v + res[idx];
            }
        }
    }
}

// ---------------- MFMA windowed attention ----------------
// block = one window (256 threads, 4 waves); wave w handles heads 2w, 2w+1.
// qkv: bf16 [T][768], out: bf16 [T][256]
__global__ __launch_bounds__(256) void attn_kernel(
    const u16* __restrict__ qkv, const float* __restrict__ rpb,
    u16* __restrict__ outb, int shift)
{
    __shared__ u16 Vt[8 * 2048];      // head h: Vt[d][k] swizzled: idx = h*2048 + d*64 + (k ^ ((d&7)<<3))
    __shared__ u16 Pl[4 * 64 * 68];   // per-wave P[64][68] bf16
    __shared__ float biasl[8 * 176];  // head h: biasl[h*176 + rel]
    __shared__ int tok[64];

    const int t = threadIdx.x;
    const int w = t >> 6;
    const int l = t & 63;
    const int c15 = l & 15, g = l >> 4;
    const int win = blockIdx.x;
    const int wj = win & 15, wi = (win >> 4) & 15, bb = win >> 8;

    if (t < 64) {
        int qq = t > 48 ? 48 : t;
        int i = div7(qq), j = qq - i*7;
        int rr = wi*7 + i + shift; if (rr >= 112) rr -= 112;
        int cc = wj*7 + j + shift; if (cc >= 112) cc -= 112;
        tok[t] = bb*12544 + rr*112 + cc;
    }
    for (int i = t; i < 1352; i += 256) {
        int h2 = i & 7, r2 = i >> 3;
        biasl[h2*176 + r2] = rpb[i];
    }
    __syncthreads();

    u16* Pw = Pl + w * 64 * 68;

    #pragma unroll 1
    for (int hh = 0; hh < 2; ++hh) {
        const int h = 2*w + hh;

        // ---- stage V transposed (wave-private head region) ----
        {
            u16x8 vreg[4];
            if (l < 49) {
                const u16x8* vs = (const u16x8*)(qkv + (size_t)tok[l]*768 + 512 + h*32);
                #pragma unroll
                for (int c4 = 0; c4 < 4; ++c4) vreg[c4] = vs[c4];
            } else {
                #pragma unroll
                for (int c4 = 0; c4 < 4; ++c4) vreg[c4] = (u16x8){0,0,0,0,0,0,0,0};
            }
            u16* vt = Vt + h*2048;
            #pragma unroll
            for (int c4 = 0; c4 < 4; ++c4)
                #pragma unroll
                for (int e = 0; e < 8; ++e)
                    vt[(c4*8 + e)*64 + (l ^ (e << 3))] = vreg[c4][e];
        }
        asm volatile("s_waitcnt lgkmcnt(0)" ::: "memory");

        // ---- Q, K fragments straight from global ----
        bf16x8 aq[4], bk[4];
        #pragma unroll
        for (int mt = 0; mt < 4; ++mt)
            aq[mt] = *(const bf16x8*)(qkv + (size_t)tok[mt*16 + c15]*768 + h*32 + g*8);
        #pragma unroll
        for (int nt = 0; nt < 4; ++nt)
            bk[nt] = *(const bf16x8*)(qkv + (size_t)tok[nt*16 + c15]*768 + 256 + h*32 + g*8);

        // ---- S = Q K^T ----
        f32x4 acc[4][4];
        #pragma unroll
        for (int mt = 0; mt < 4; ++mt)
            #pragma unroll
            for (int nt = 0; nt < 4; ++nt) acc[mt][nt] = (f32x4){0.f,0.f,0.f,0.f};
        #pragma unroll
        for (int mt = 0; mt < 4; ++mt)
            #pragma unroll
            for (int nt = 0; nt < 4; ++nt)
                acc[mt][nt] = __builtin_amdgcn_mfma_f32_16x16x32_bf16(aq[mt], bk[nt], acc[mt][nt], 0, 0, 0);

        // ---- per-key info ----
        int ikv[4], jkv[4], regk[4];
        bool kval[4];
        #pragma unroll
        for (int nt = 0; nt < 4; ++nt) {
            int key = nt*16 + c15;
            kval[nt] = key < 49;
            int kb = kval[nt] ? key : 48;
            int ik = div7(kb), jk = kb - ik*7;
            ikv[nt] = ik; jkv[nt] = jk;
            regk[nt] = 0;
            if (shift > 0) {
                int rr = wi*7 + ik, cc = wj*7 + jk;
                int hr2 = rr < 105 ? 0 : (rr < 109 ? 1 : 2);
                int wr2 = cc < 105 ? 0 : (cc < 109 ? 1 : 2);
                regk[nt] = hr2*3 + wr2;
            }
        }
        const float* bh = biasl + h*176;

        // ---- bias + mask + softmax + normalized bf16 P -> LDS ----
        #pragma unroll
        for (int mt = 0; mt < 4; ++mt) {
            #pragma unroll
            for (int j = 0; j < 4; ++j) {
                int q = mt*16 + g*4 + j;
                int qb = q > 48 ? 48 : q;
                int iq = div7(qb), jq = qb - iq*7;
                int regq = 0;
                if (shift > 0) {
                    int rr = wi*7 + iq, cc = wj*7 + jq;
                    int hr2 = rr < 105 ? 0 : (rr < 109 ? 1 : 2);
                    int wr2 = cc < 105 ? 0 : (cc < 109 ? 1 : 2);
                    regq = hr2*3 + wr2;
                }
                float vr[4];
                #pragma unroll
                for (int nt = 0; nt < 4; ++nt) {
                    float v = acc[mt][nt][j] * 0.17677669529663687f;
                    if (kval[nt]) {
                        v += bh[(iq - ikv[nt] + 6)*13 + (jq - jkv[nt] + 6)];
                        if (shift > 0 && regq != regk[nt]) v -= 100.0f;
                    } else v = -1e30f;
                    vr[nt] = v;
                }
                float mx = fmaxf(fmaxf(vr[0], vr[1]), fmaxf(vr[2], vr[3]));
                mx = fmaxf(mx, __shfl_xor(mx, 1));
                mx = fmaxf(mx, __shfl_xor(mx, 2));
                mx = fmaxf(mx, __shfl_xor(mx, 4));
                mx = fmaxf(mx, __shfl_xor(mx, 8));
                float e0 = __expf(vr[0] - mx), e1 = __expf(vr[1] - mx);
                float e2 = __expf(vr[2] - mx), e3 = __expf(vr[3] - mx);
                float sm = (e0 + e1) + (e2 + e3);
                sm += __shfl_xor(sm, 1);
                sm += __shfl_xor(sm, 2);
                sm += __shfl_xor(sm, 4);
                sm += __shfl_xor(sm, 8);
                float inv = __builtin_amdgcn_rcpf(sm);
                Pw[q*68 +  0 + c15] = f2bf(e0 * inv);
                Pw[q*68 + 16 + c15] = f2bf(e1 * inv);
                Pw[q*68 + 32 + c15] = f2bf(e2 * inv);
                Pw[q*68 + 48 + c15] = f2bf(e3 * inv);
            }
        }
        asm volatile("s_waitcnt lgkmcnt(0)" ::: "memory");

        // ---- O = P V ----
        bf16x8 pa[4][2];
        #pragma unroll
        for (int mt = 0; mt < 4; ++mt)
            #pragma unroll
            for (int s = 0; s < 2; ++s) {
                const u16* pp = Pw + (mt*16 + c15)*68 + s*32 + g*8;
                union { struct { u16x4 lo, hi; } p; bf16x8 v; } u;
                u.p.lo = *(const u16x4*)pp;
                u.p.hi = *(const u16x4*)(pp + 4);
                pa[mt][s] = u.v;
            }
        bf16x8 vb[2][2];
        const u16* vt = Vt + h*2048;
        #pragma unroll
        for (int nt = 0; nt < 2; ++nt)
            #pragma unroll
            for (int s = 0; s < 2; ++s) {
                int d = nt*16 + c15;
                vb[nt][s] = *(const bf16x8*)(vt + d*64 + ((s*32 + g*8) ^ ((d & 7) << 3)));
            }
        f32x4 o[4][2];
        #pragma unroll
        for (int mt = 0; mt < 4; ++mt)
            #pragma unroll
            for (int nt = 0; nt < 2; ++nt) o[mt][nt] = (f32x4){0.f,0.f,0.f,0.f};
        #pragma unroll
        for (int s = 0; s < 2; ++s)
            #pragma unroll
            for (int mt = 0; mt < 4; ++mt)
                #pragma unroll
                for (int nt = 0; nt < 2; ++nt)
                    o[mt][nt] = __builtin_amdgcn_mfma_f32_16x16x32_bf16(pa[mt][s], vb[nt][s], o[mt][nt], 0, 0, 0);

        // ---- store ----
        #pragma unroll
        for (int mt = 0; mt < 4; ++mt) {
            #pragma unroll
            for (int j = 0; j < 4; ++j) {
                int q = mt*16 + g*4 + j;
                if (q < 49) {
                    u16* dst = outb + (size_t)tok[q]*256 + h*32;
                    dst[c15]      = f2bf(o[mt][0][j]);
                    dst[16 + c15] = f2bf(o[mt][1][j]);
                }
            }
        }
    }
}

// ---------------- host ----------------
extern "C" void kernel_launch(void* const* d_in, const int* in_sizes, int n_in,
                              void* d_out, int out_size, void* d_ws, size_t ws_size,
                              hipStream_t stream) {
    const float* x_in   = (const float*)d_in[0];
    const float* ln1_w  = (const float*)d_in[1];
    const float* ln1_b  = (const float*)d_in[2];
    const float* qkv_w  = (const float*)d_in[3];
    const float* qkv_b  = (const float*)d_in[4];
    const float* proj_w = (const float*)d_in[5];
    const float* proj_b = (const float*)d_in[6];
    const float* rpb    = (const float*)d_in[7];
    const float* ln2_w  = (const float*)d_in[8];
    const float* ln2_b  = (const float*)d_in[9];
    const float* mlp_w1 = (const float*)d_in[10];
    const float* mlp_b1 = (const float*)d_in[11];
    const float* mlp_w2 = (const float*)d_in[12];
    const float* mlp_b2 = (const float*)d_in[13];
    float* xout = (float*)d_out;

    char* p = (char*)d_ws;
    u16* wq = (u16*)p;  p += (size_t)2*768*256*2;
    u16* wp = (u16*)p;  p += (size_t)2*256*256*2;
    u16* w1 = (u16*)p;  p += (size_t)2*1024*256*2;
    u16* w2 = (u16*)p;  p += (size_t)2*256*1024*2;
    u16* buf_y   = (u16*)p; p += (size_t)T_TOK*256*2;
    u16* buf_big = (u16*)p;

    {
        int n;
        n = 2*768*256;  cvt_kernel<<<(n+255)/256, 256, 0, stream>>>(qkv_w,  wq, n);
        n = 2*256*256;  cvt_kernel<<<(n+255)/256, 256, 0, stream>>>(proj_w, wp, n);
        n = 2*1024*256; cvt_kernel<<<(n+255)/256, 256, 0, stream>>>(mlp_w1, w1, n);
        n = 2*256*1024; cvt_kernel<<<(n+255)/256, 256, 0, stream>>>(mlp_w2, w2, n);
    }

    for (int i = 0; i < 2; ++i) {
        const int shift = (i == 0) ? 0 : 3;
        const float* xcur = (i == 0) ? x_in : xout;

        ln_kernel<<<T_TOK/4, 256, 0, stream>>>(xcur, ln1_w + i*256, ln1_b + i*256, buf_y);
        gemm_kernel<0><<<dim3(6, T_TOK/128), 256, 0, stream>>>(
            buf_y, wq + (size_t)i*768*256, qkv_b + i*768, buf_big, nullptr, 768, 256);
        attn_kernel<<<2048, 256, 0, stream>>>(buf_big, rpb + i*169*8, buf_y, shift);
        gemm_kernel<2><<<dim3(2, T_TOK/128), 256, 0, stream>>>(
            buf_y, wp + (size_t)i*256*256, proj_b + i*256, xout, xcur, 256, 256);
        ln_kernel<<<T_TOK/4, 256, 0, stream>>>(xout, ln2_w + i*256, ln2_b + i*256, buf_y);
        gemm_kernel<1><<<dim3(8, T_TOK/128), 256, 0, stream>>>(
            buf_y, w1 + (size_t)i*1024*256, mlp_b1 + i*1024, buf_big, nullptr, 1024, 256);
        gemm_kernel<2><<<dim3(2, T_TOK/128), 256, 0, stream>>>(
            buf_big, w2 + (size_t)i*256*1024, mlp_b2 + i*256, xout, xout, 256, 1024);
    }
}

// Round 3
// 1085.341 us; speedup vs baseline: 1.2015x; 1.2015x over previous
//
#include <hip/hip_runtime.h>

typedef unsigned short u16;
typedef unsigned int u32;
typedef __attribute__((ext_vector_type(8))) short bf16x8;
typedef __attribute__((ext_vector_type(4))) float f32x4;
typedef __attribute__((ext_vector_type(16))) float f32x16;
typedef __attribute__((ext_vector_type(8))) unsigned short u16x8;
typedef const __attribute__((address_space(1))) void gvoid;
typedef __attribute__((address_space(3))) void svoid;

#define T_TOK 100352
#define CDIM 256
#define ATTN_SCALE 0.17677669529663687f

__device__ __forceinline__ u16 f2bf(float f) {
    u32 u = __float_as_uint(f);
    u32 r = (u + 0x7fffu + ((u >> 16) & 1u)) >> 16;
    return (u16)r;
}
__device__ __forceinline__ float bf2f(u16 h) {
    return __uint_as_float(((u32)h) << 16);
}
__device__ __forceinline__ float gelu_f(float x) {
    return 0.5f * x * (1.0f + erff(x * 0.70710678118654752f));
}
__device__ __forceinline__ int div7(int q) { return (q * 37) >> 8; }  // exact for 0..48
__device__ __forceinline__ int reg3(int r) { return r < 105 ? 0 : (r < 109 ? 1 : 2); }

// ---------------- fp32 -> bf16 weight conversion ----------------
__global__ void cvt_kernel(const float* __restrict__ in, u16* __restrict__ out, int n) {
    int i = blockIdx.x * 256 + threadIdx.x;
    if (i < n) out[i] = f2bf(in[i]);
}

// ---------------- LayerNorm (fp32 in, bf16 out) ----------------
__global__ __launch_bounds__(256) void ln_kernel(
    const float* __restrict__ X, const float* __restrict__ w,
    const float* __restrict__ b, u16* __restrict__ Y)
{
    int wid = threadIdx.x >> 6, l = threadIdx.x & 63;
    int t = blockIdx.x * 4 + wid;
    const float4 x4 = ((const float4*)(X + (size_t)t * CDIM))[l];
    float s  = x4.x + x4.y + x4.z + x4.w;
    float s2 = x4.x*x4.x + x4.y*x4.y + x4.z*x4.z + x4.w*x4.w;
    #pragma unroll
    for (int o = 32; o; o >>= 1) { s += __shfl_xor(s, o); s2 += __shfl_xor(s2, o); }
    float mean = s * (1.0f/256.0f);
    float var  = s2 * (1.0f/256.0f) - mean*mean;
    float rstd = rsqrtf(var + 1e-5f);
    float4 w4 = ((const float4*)w)[l];
    float4 b4 = ((const float4*)b)[l];
    ushort4 o4;
    o4.x = f2bf((x4.x - mean)*rstd*w4.x + b4.x);
    o4.y = f2bf((x4.y - mean)*rstd*w4.y + b4.y);
    o4.z = f2bf((x4.z - mean)*rstd*w4.z + b4.z);
    o4.w = f2bf((x4.w - mean)*rstd*w4.w + b4.w);
    ((ushort4*)(Y + (size_t)t * CDIM))[l] = o4;
}

// ---------------- bf16 MFMA GEMM:  out[M,N] = A[M,K] @ B[N,K]^T + bias ----------------
template<int EPI>
__global__ __launch_bounds__(256) void gemm_kernel(
    const u16* __restrict__ A, const u16* __restrict__ Bw,
    const float* __restrict__ bias, void* __restrict__ outp,
    const float* __restrict__ res, int N, int K)
{
    __shared__ u16 lsA[128 * 32];
    __shared__ u16 lsB[128 * 32];
    const int l = threadIdx.x & 63;
    const int w = threadIdx.x >> 6;
    const int mT = blockIdx.y, nT = blockIdx.x;
    const int wr = w >> 1, wc = w & 1;

    f32x4 acc[4][4];
    #pragma unroll
    for (int m = 0; m < 4; ++m)
        #pragma unroll
        for (int n = 0; n < 4; ++n) acc[m][n] = (f32x4){0.f,0.f,0.f,0.f};

    const int rsub = l >> 2;
    const int ksub = (l & 3) * 8;

    for (int kt = 0; kt < K; kt += 32) {
        __syncthreads();
        #pragma unroll
        for (int i = 0; i < 2; ++i) {
            int row = i*64 + w*16 + rsub;
            const u16* ga = A  + (size_t)(mT*128 + row) * K + kt + ksub;
            const u16* gb = Bw + (size_t)(nT*128 + row) * K + kt + ksub;
            u16* la = lsA + i*2048 + w*512;
            u16* lb = lsB + i*2048 + w*512;
            __builtin_amdgcn_global_load_lds((gvoid*)ga, (svoid*)la, 16, 0, 0);
            __builtin_amdgcn_global_load_lds((gvoid*)gb, (svoid*)lb, 16, 0, 0);
        }
        __syncthreads();
        const int lr = l & 15;
        const int lk = (l >> 4) * 8;
        bf16x8 a[4], b[4];
        #pragma unroll
        for (int m = 0; m < 4; ++m) a[m] = *(const bf16x8*)&lsA[(wr*64 + m*16 + lr)*32 + lk];
        #pragma unroll
        for (int n = 0; n < 4; ++n) b[n] = *(const bf16x8*)&lsB[(wc*64 + n*16 + lr)*32 + lk];
        #pragma unroll
        for (int m = 0; m < 4; ++m)
            #pragma unroll
            for (int n = 0; n < 4; ++n)
                acc[m][n] = __builtin_amdgcn_mfma_f32_16x16x32_bf16(a[m], b[n], acc[m][n], 0, 0, 0);
    }

    const int lr4 = (l >> 4) * 4;
    const int lcn = l & 15;
    #pragma unroll
    for (int m = 0; m < 4; ++m) {
        #pragma unroll
        for (int n = 0; n < 4; ++n) {
            int row0 = mT*128 + wr*64 + m*16 + lr4;
            int col  = nT*128 + wc*64 + n*16 + lcn;
            float bb = bias[col];
            #pragma unroll
            for (int j = 0; j < 4; ++j) {
                size_t idx = (size_t)(row0 + j) * N + col;
                float v = acc[m][n][j] + bb;
                if (EPI == 0)      ((u16*)outp)[idx] = f2bf(v);
                else if (EPI == 1) ((u16*)outp)[idx] = f2bf(gelu_f(v));
                else               ((float*)outp)[idx] = v + res[idx];
            }
        }
    }
}

// ---------------- MFMA windowed attention, swapped-QK^T 32x32 ----------------
// block = one window (256 threads, 4 waves); wave w handles heads 2w, 2w+1.
// S^T = mfma(K,Q): lane holds its own q-column -> in-register softmax ->
// pack bf16 + v_permlane32_swap -> PV A-frag. No P through LDS.
__global__ __launch_bounds__(256) void attn_kernel(
    const u16* __restrict__ qkv, const float* __restrict__ rpb,
    u16* __restrict__ outb, int shift)
{
    __shared__ u16 Vt[8][2048];       // head h: Vt[h][d*64 + (k ^ ((d&7)<<3))]
    __shared__ float biasl[8 * 176];
    __shared__ int tok[64];

    const int t = threadIdx.x;
    const int w = t >> 6;
    const int l = t & 63;
    const int lo = l & 31;
    const int hi = l >> 5;
    const int win = blockIdx.x;
    const int wj = win & 15, wi = (win >> 4) & 15, bb = win >> 8;

    if (t < 64) {
        int qq = t > 48 ? 48 : t;
        int i = div7(qq), j = qq - i*7;
        int rr = wi*7 + i + shift; if (rr >= 112) rr -= 112;
        int cc = wj*7 + j + shift; if (cc >= 112) cc -= 112;
        tok[t] = bb*12544 + rr*112 + cc;
    }
    for (int i2 = t; i2 < 1352; i2 += 256)
        biasl[(i2 & 7)*176 + (i2 >> 3)] = rpb[i2];
    __syncthreads();

    // per-lane q info (q = nt*32 + lo)
    int iqv[2], jqv[2], regq[2];
    #pragma unroll
    for (int nt = 0; nt < 2; ++nt) {
        int q = nt*32 + lo; int qb = q > 48 ? 48 : q;
        int iq = div7(qb), jq = qb - iq*7;
        iqv[nt] = iq; jqv[nt] = jq;
        regq[nt] = 0;
        if (shift > 0) regq[nt] = reg3(wi*7 + iq)*3 + reg3(wj*7 + jq);
    }

    #pragma unroll 1
    for (int hh = 0; hh < 2; ++hh) {
        const int h = 2*w + hh;

        // ---- stage V^T (wave-private head region; DS per-wave in-order) ----
        {
            u16x8 vreg[4];
            if (l < 49) {
                const u16x8* vs = (const u16x8*)(qkv + (size_t)tok[l]*768 + 512 + h*32);
                #pragma unroll
                for (int c4 = 0; c4 < 4; ++c4) vreg[c4] = vs[c4];
            } else {
                #pragma unroll
                for (int c4 = 0; c4 < 4; ++c4) vreg[c4] = (u16x8){0,0,0,0,0,0,0,0};
            }
            u16* vt = &Vt[h][0];
            #pragma unroll
            for (int c4 = 0; c4 < 4; ++c4)
                #pragma unroll
                for (int e = 0; e < 8; ++e)
                    vt[(c4*8 + e)*64 + (l ^ (e << 3))] = vreg[c4][e];
        }

        // ---- K, Q fragments straight from global ----
        // K-frag (A, m = key): lane lo = key token (+mt*32), elems d = td*16 + hi*8 + e
        // Q-frag (B, n = query): lane lo = query (+nt*32)
        bf16x8 kf[2][2], qf[2][2];
        #pragma unroll
        for (int mt = 0; mt < 2; ++mt)
            #pragma unroll
            for (int td = 0; td < 2; ++td)
                kf[mt][td] = *(const bf16x8*)(qkv + (size_t)tok[mt*32 + lo]*768 + 256 + h*32 + td*16 + hi*8);
        #pragma unroll
        for (int nt = 0; nt < 2; ++nt)
            #pragma unroll
            for (int td = 0; td < 2; ++td)
                qf[nt][td] = *(const bf16x8*)(qkv + (size_t)tok[nt*32 + lo]*768 + h*32 + td*16 + hi*8);

        // ---- S^T = K @ Q^T : C[k][q], col=q=lo, row=k=(reg&3)+8*(reg>>2)+4*hi ----
        f32x16 s[2][2];
        #pragma unroll
        for (int mt = 0; mt < 2; ++mt)
            #pragma unroll
            for (int nt = 0; nt < 2; ++nt) {
                f32x16 z;
                #pragma unroll
                for (int i = 0; i < 16; ++i) z[i] = 0.f;
                s[mt][nt] = z;
            }
        #pragma unroll
        for (int td = 0; td < 2; ++td)
            #pragma unroll
            for (int mt = 0; mt < 2; ++mt)
                #pragma unroll
                for (int nt = 0; nt < 2; ++nt)
                    s[mt][nt] = __builtin_amdgcn_mfma_f32_32x32x16_bf16(kf[mt][td], qf[nt][td], s[mt][nt], 0, 0, 0);

        // ensure V^T staging is complete before PV reads (same-wave DS ordering + fence)
        asm volatile("s_waitcnt lgkmcnt(0)" ::: "memory");
        __builtin_amdgcn_sched_barrier(0);

        // ---- scale + bias + mask + padding ----
        const float* bh = biasl + h*176;
        #pragma unroll
        for (int mt = 0; mt < 2; ++mt) {
            #pragma unroll
            for (int i = 0; i < 16; ++i) {
                int r = (i & 3) + 8*(i >> 2) + 4*hi;
                int k = mt*32 + r;
                bool valid = k < 49;
                int kb = valid ? k : 48;
                int ik = div7(kb), jk = kb - ik*7;
                int regk = 0;
                if (shift > 0) regk = reg3(wi*7 + ik)*3 + reg3(wj*7 + jk);
                #pragma unroll
                for (int nt = 0; nt < 2; ++nt) {
                    float v = s[mt][nt][i] * ATTN_SCALE
                            + bh[(iqv[nt] - ik + 6)*13 + (jqv[nt] - jk + 6)];
                    if (shift > 0 && regq[nt] != regk) v -= 100.0f;
                    if (!valid) v = -1e30f;
                    s[mt][nt][i] = v;
                }
            }
        }

        // ---- per-q softmax (32 local values + one shfl_xor(32)) + PV + store ----
        #pragma unroll
        for (int nt = 0; nt < 2; ++nt) {
            float mx = -1e30f;
            #pragma unroll
            for (int i = 0; i < 16; ++i) mx = fmaxf(mx, fmaxf(s[0][nt][i], s[1][nt][i]));
            mx = fmaxf(mx, __shfl_xor(mx, 32));
            float sum = 0.f;
            #pragma unroll
            for (int mt = 0; mt < 2; ++mt)
                #pragma unroll
                for (int i = 0; i < 16; ++i) {
                    float e = __expf(s[mt][nt][i] - mx);
                    s[mt][nt][i] = e;
                    sum += e;
                }
            sum += __shfl_xor(sum, 32);
            float inv = __builtin_amdgcn_rcpf(sum);

            // pack P to bf16 pairs: pk[mt][j] covers rows {2j,2j+1 pattern} per C-layout
            u32 pk[2][8];
            #pragma unroll
            for (int mt = 0; mt < 2; ++mt)
                #pragma unroll
                for (int j = 0; j < 8; ++j)
                    pk[mt][j] = (u32)f2bf(s[mt][nt][2*j] * inv)
                              | ((u32)f2bf(s[mt][nt][2*j + 1] * inv) << 16);

            // PV: O[q][d] = sum_k P[q][k] V[k][d]
            f32x16 o;
            #pragma unroll
            for (int i = 0; i < 16; ++i) o[i] = 0.f;
            #pragma unroll
            for (int kt = 0; kt < 4; ++kt) {
                const int mt = kt >> 1;
                const int base = (kt & 1) * 4;
                u32 a0 = pk[mt][base + 0], a1 = pk[mt][base + 1];
                u32 a2 = pk[mt][base + 2], a3 = pk[mt][base + 3];
                asm volatile("v_permlane32_swap_b32 %0, %1" : "+v"(a0), "+v"(a2));
                asm volatile("v_permlane32_swap_b32 %0, %1" : "+v"(a1), "+v"(a3));
                union { u32 u[4]; bf16x8 v; } pf;
                pf.u[0] = a0; pf.u[1] = a1; pf.u[2] = a2; pf.u[3] = a3;
                bf16x8 vb = *(const bf16x8*)(&Vt[h][lo*64 + ((kt*16 + hi*8) ^ ((lo & 7) << 3))]);
                o = __builtin_amdgcn_mfma_f32_32x32x16_bf16(pf.v, vb, o, 0, 0, 0);
            }

            // store: col = d = lo, row = q = nt*32 + (i&3)+8*(i>>2)+4*hi
            #pragma unroll
            for (int i = 0; i < 16; ++i) {
                int q = nt*32 + (i & 3) + 8*(i >> 2) + 4*hi;
                if (q < 49)
                    outb[(size_t)tok[q]*256 + h*32 + lo] = f2bf(o[i]);
            }
        }
    }
}

// ---------------- host ----------------
extern "C" void kernel_launch(void* const* d_in, const int* in_sizes, int n_in,
                              void* d_out, int out_size, void* d_ws, size_t ws_size,
                              hipStream_t stream) {
    const float* x_in   = (const float*)d_in[0];
    const float* ln1_w  = (const float*)d_in[1];
    const float* ln1_b  = (const float*)d_in[2];
    const float* qkv_w  = (const float*)d_in[3];
    const float* qkv_b  = (const float*)d_in[4];
    const float* proj_w = (const float*)d_in[5];
    const float* proj_b = (const float*)d_in[6];
    const float* rpb    = (const float*)d_in[7];
    const float* ln2_w  = (const float*)d_in[8];
    const float* ln2_b  = (const float*)d_in[9];
    const float* mlp_w1 = (const float*)d_in[10];
    const float* mlp_b1 = (const float*)d_in[11];
    const float* mlp_w2 = (const float*)d_in[12];
    const float* mlp_b2 = (const float*)d_in[13];
    float* xout = (float*)d_out;

    char* p = (char*)d_ws;
    u16* wq = (u16*)p;  p += (size_t)2*768*256*2;
    u16* wp = (u16*)p;  p += (size_t)2*256*256*2;
    u16* w1 = (u16*)p;  p += (size_t)2*1024*256*2;
    u16* w2 = (u16*)p;  p += (size_t)2*256*1024*2;
    u16* buf_y   = (u16*)p; p += (size_t)T_TOK*256*2;
    u16* buf_big = (u16*)p;

    {
        int n;
        n = 2*768*256;  cvt_kernel<<<(n+255)/256, 256, 0, stream>>>(qkv_w,  wq, n);
        n = 2*256*256;  cvt_kernel<<<(n+255)/256, 256, 0, stream>>>(proj_w, wp, n);
        n = 2*1024*256; cvt_kernel<<<(n+255)/256, 256, 0, stream>>>(mlp_w1, w1, n);
        n = 2*256*1024; cvt_kernel<<<(n+255)/256, 256, 0, stream>>>(mlp_w2, w2, n);
    }

    for (int i = 0; i < 2; ++i) {
        const int shift = (i == 0) ? 0 : 3;
        const float* xcur = (i == 0) ? x_in : xout;

        ln_kernel<<<T_TOK/4, 256, 0, stream>>>(xcur, ln1_w + i*256, ln1_b + i*256, buf_y);
        gemm_kernel<0><<<dim3(6, T_TOK/128), 256, 0, stream>>>(
            buf_y, wq + (size_t)i*768*256, qkv_b + i*768, buf_big, nullptr, 768, 256);
        attn_kernel<<<2048, 256, 0, stream>>>(buf_big, rpb + i*169*8, buf_y, shift);
        gemm_kernel<2><<<dim3(2, T_TOK/128), 256, 0, stream>>>(
            buf_y, wp + (size_t)i*256*256, proj_b + i*256, xout, xcur, 256, 256);
        ln_kernel<<<T_TOK/4, 256, 0, stream>>>(xout, ln2_w + i*256, ln2_b + i*256, buf_y);
        gemm_kernel<1><<<dim3(8, T_TOK/128), 256, 0, stream>>>(
            buf_y, w1 + (size_t)i*1024*256, mlp_b1 + i*1024, buf_big, nullptr, 1024, 256);
        gemm_kernel<2><<<dim3(2, T_TOK/128), 256, 0, stream>>>(
            buf_big, w2 + (size_t)i*256*1024, mlp_b2 + i*256, xout, xout, 256, 1024);
    }
}

// Round 4
// 1051.622 us; speedup vs baseline: 1.2400x; 1.0321x over previous
//
#include <hip/hip_runtime.h>

typedef unsigned short u16;
typedef unsigned int u32;
typedef __attribute__((ext_vector_type(8))) short bf16x8;
typedef __attribute__((ext_vector_type(4))) float f32x4;
typedef __attribute__((ext_vector_type(16))) float f32x16;
typedef __attribute__((ext_vector_type(8))) unsigned short u16x8;
typedef const __attribute__((address_space(1))) void gvoid;
typedef __attribute__((address_space(3))) void svoid;

#define T_TOK 100352
#define CDIM 256
#define ATTN_SCALE 0.17677669529663687f

__device__ __forceinline__ u16 f2bf(float f) {
    u32 u = __float_as_uint(f);
    u32 r = (u + 0x7fffu + ((u >> 16) & 1u)) >> 16;
    return (u16)r;
}
__device__ __forceinline__ float bf2f(u16 h) {
    return __uint_as_float(((u32)h) << 16);
}
__device__ __forceinline__ float gelu_f(float x) {
    return 0.5f * x * (1.0f + erff(x * 0.70710678118654752f));
}
__device__ __forceinline__ int div7(int q) { return (q * 37) >> 8; }  // exact for 0..48
__device__ __forceinline__ int reg3(int r) { return r < 105 ? 0 : (r < 109 ? 1 : 2); }

// ---------------- fp32 -> bf16 weight conversion ----------------
__global__ void cvt_kernel(const float* __restrict__ in, u16* __restrict__ out, int n) {
    int i = blockIdx.x * 256 + threadIdx.x;
    if (i < n) out[i] = f2bf(in[i]);
}

// ---------------- LayerNorm (fp32 in, bf16 out) ----------------
__global__ __launch_bounds__(256) void ln_kernel(
    const float* __restrict__ X, const float* __restrict__ w,
    const float* __restrict__ b, u16* __restrict__ Y)
{
    int wid = threadIdx.x >> 6, l = threadIdx.x & 63;
    int t = blockIdx.x * 4 + wid;
    const float4 x4 = ((const float4*)(X + (size_t)t * CDIM))[l];
    float s  = x4.x + x4.y + x4.z + x4.w;
    float s2 = x4.x*x4.x + x4.y*x4.y + x4.z*x4.z + x4.w*x4.w;
    #pragma unroll
    for (int o = 32; o; o >>= 1) { s += __shfl_xor(s, o); s2 += __shfl_xor(s2, o); }
    float mean = s * (1.0f/256.0f);
    float var  = s2 * (1.0f/256.0f) - mean*mean;
    float rstd = rsqrtf(var + 1e-5f);
    float4 w4 = ((const float4*)w)[l];
    float4 b4 = ((const float4*)b)[l];
    ushort4 o4;
    o4.x = f2bf((x4.x - mean)*rstd*w4.x + b4.x);
    o4.y = f2bf((x4.y - mean)*rstd*w4.y + b4.y);
    o4.z = f2bf((x4.z - mean)*rstd*w4.z + b4.z);
    o4.w = f2bf((x4.w - mean)*rstd*w4.w + b4.w);
    ((ushort4*)(Y + (size_t)t * CDIM))[l] = o4;
}

// ---------------- bf16 MFMA GEMM:  out[M,N] = A[M,K] @ B[N,K]^T + bias ----------------
// 128x128 tile, BK=64, double-buffered LDS, min-2-phase pipeline:
// ds_read(cur) -> STAGE(next) -> MFMA -> vmcnt(0) -> s_barrier.
// LDS layout: linear 16B granules; granule (r,g) holds global granule (r, g^(r&7)).
template<int EPI>
__global__ __launch_bounds__(256) void gemm_kernel(
    const u16* __restrict__ A, const u16* __restrict__ Bw,
    const float* __restrict__ bias, void* __restrict__ outp,
    const float* __restrict__ res, int N, int K, int nTn)
{
    __shared__ __align__(16) u16 lds[2][2][128 * 64];
    const int tid = threadIdx.x;
    const int l = tid & 63;
    const int w = tid >> 6;
    const int wr = w >> 1, wc = w & 1;

    // XCD-chunked swizzle (grid always divisible by 8 here)
    const int nBlocks = gridDim.x;
    const int cpx = nBlocks >> 3;
    const int lin = (blockIdx.x & 7) * cpx + (blockIdx.x >> 3);
    const int nT = lin % nTn;
    const int mT = lin / nTn;

    f32x4 acc[4][4];
    #pragma unroll
    for (int m = 0; m < 4; ++m)
        #pragma unroll
        for (int n = 0; n < 4; ++n) acc[m][n] = (f32x4){0.f,0.f,0.f,0.f};

    const int sr = tid >> 3;          // staging row  (tid -> granule tid: r=tid>>3, g=tid&7)
    const int sg = tid & 7;

    #define STAGE(buf, kt)                                                              \
        {                                                                               \
            _Pragma("unroll")                                                           \
            for (int c = 0; c < 4; ++c) {                                               \
                int r = c*32 + sr;                                                      \
                int gsrc = sg ^ (r & 7);                                                \
                const u16* ga = A  + (size_t)(mT*128 + r) * K + (kt) + gsrc*8;          \
                const u16* gb = Bw + (size_t)(nT*128 + r) * K + (kt) + gsrc*8;          \
                u16* la = &lds[buf][0][(c*256 + w*64) * 8];                              \
                u16* lb = &lds[buf][1][(c*256 + w*64) * 8];                              \
                __builtin_amdgcn_global_load_lds((gvoid*)ga, (svoid*)la, 16, 0, 0);     \
                __builtin_amdgcn_global_load_lds((gvoid*)gb, (svoid*)lb, 16, 0, 0);     \
            }                                                                           \
        }

    const int nSteps = K >> 6;
    int cur = 0;

    // prologue: stage tile 0
    STAGE(0, 0);
    asm volatile("s_waitcnt vmcnt(0)" ::: "memory");
    __builtin_amdgcn_s_barrier();
    asm volatile("" ::: "memory");

    const int lr = l & 15, gq = l >> 4;
    for (int t = 0; t < nSteps; ++t) {
        // ds_read fragments of current buffer (issued before STAGE; LDS-aliasing
        // keeps them ordered before next-tile writes)
        bf16x8 a[2][4], b[2][4];
        #pragma unroll
        for (int kk = 0; kk < 2; ++kk) {
            #pragma unroll
            for (int m = 0; m < 4; ++m) {
                int r = wr*64 + m*16 + lr;
                int g = kk*4 + gq;
                a[kk][m] = *(const bf16x8*)&lds[cur][0][r*64 + (g ^ (r & 7))*8];
            }
            #pragma unroll
            for (int n = 0; n < 4; ++n) {
                int r = wc*64 + n*16 + lr;
                int g = kk*4 + gq;
                b[kk][n] = *(const bf16x8*)&lds[cur][1][r*64 + (g ^ (r & 7))*8];
            }
        }
        // issue next tile's loads (overlap with MFMA below)
        if (t + 1 < nSteps) STAGE(cur ^ 1, (t + 1) * 64);

        __builtin_amdgcn_s_setprio(1);
        #pragma unroll
        for (int kk = 0; kk < 2; ++kk)
            #pragma unroll
            for (int m = 0; m < 4; ++m)
                #pragma unroll
                for (int n = 0; n < 4; ++n)
                    acc[m][n] = __builtin_amdgcn_mfma_f32_16x16x32_bf16(a[kk][m], b[kk][n], acc[m][n], 0, 0, 0);
        __builtin_amdgcn_s_setprio(0);

        asm volatile("s_waitcnt vmcnt(0)" ::: "memory");
        __builtin_amdgcn_s_barrier();
        asm volatile("" ::: "memory");
        cur ^= 1;
    }
    #undef STAGE

    const int lr4 = gq * 4;
    const int lcn = lr;
    #pragma unroll
    for (int m = 0; m < 4; ++m) {
        #pragma unroll
        for (int n = 0; n < 4; ++n) {
            int row0 = mT*128 + wr*64 + m*16 + lr4;
            int col  = nT*128 + wc*64 + n*16 + lcn;
            float bb = bias[col];
            #pragma unroll
            for (int j = 0; j < 4; ++j) {
                size_t idx = (size_t)(row0 + j) * N + col;
                float v = acc[m][n][j] + bb;
                if (EPI == 0)      ((u16*)outp)[idx] = f2bf(v);
                else if (EPI == 1) ((u16*)outp)[idx] = f2bf(gelu_f(v));
                else               ((float*)outp)[idx] = v + res[idx];
            }
        }
    }
}

// ---------------- MFMA windowed attention, swapped-QK^T 32x32 ----------------
__global__ __launch_bounds__(256) void attn_kernel(
    const u16* __restrict__ qkv, const float* __restrict__ rpb,
    u16* __restrict__ outb, int shift)
{
    __shared__ u16 Vt[8][2048];       // head h: Vt[h][d*64 + (k ^ ((d&7)<<3))]
    __shared__ float biasl[8 * 176];
    __shared__ int tok[64];

    const int t = threadIdx.x;
    const int w = t >> 6;
    const int l = t & 63;
    const int lo = l & 31;
    const int hi = l >> 5;
    const int win = blockIdx.x;
    const int wj = win & 15, wi = (win >> 4) & 15, bb = win >> 8;

    if (t < 64) {
        int qq = t > 48 ? 48 : t;
        int i = div7(qq), j = qq - i*7;
        int rr = wi*7 + i + shift; if (rr >= 112) rr -= 112;
        int cc = wj*7 + j + shift; if (cc >= 112) cc -= 112;
        tok[t] = bb*12544 + rr*112 + cc;
    }
    for (int i2 = t; i2 < 1352; i2 += 256)
        biasl[(i2 & 7)*176 + (i2 >> 3)] = rpb[i2];
    __syncthreads();

    int iqv[2], jqv[2], regq[2];
    #pragma unroll
    for (int nt = 0; nt < 2; ++nt) {
        int q = nt*32 + lo; int qb = q > 48 ? 48 : q;
        int iq = div7(qb), jq = qb - iq*7;
        iqv[nt] = iq; jqv[nt] = jq;
        regq[nt] = 0;
        if (shift > 0) regq[nt] = reg3(wi*7 + iq)*3 + reg3(wj*7 + jq);
    }

    #pragma unroll 1
    for (int hh = 0; hh < 2; ++hh) {
        const int h = 2*w + hh;

        {
            u16x8 vreg[4];
            if (l < 49) {
                const u16x8* vs = (const u16x8*)(qkv + (size_t)tok[l]*768 + 512 + h*32);
                #pragma unroll
                for (int c4 = 0; c4 < 4; ++c4) vreg[c4] = vs[c4];
            } else {
                #pragma unroll
                for (int c4 = 0; c4 < 4; ++c4) vreg[c4] = (u16x8){0,0,0,0,0,0,0,0};
            }
            u16* vt = &Vt[h][0];
            #pragma unroll
            for (int c4 = 0; c4 < 4; ++c4)
                #pragma unroll
                for (int e = 0; e < 8; ++e)
                    vt[(c4*8 + e)*64 + (l ^ (e << 3))] = vreg[c4][e];
        }

        bf16x8 kf[2][2], qf[2][2];
        #pragma unroll
        for (int mt = 0; mt < 2; ++mt)
            #pragma unroll
            for (int td = 0; td < 2; ++td)
                kf[mt][td] = *(const bf16x8*)(qkv + (size_t)tok[mt*32 + lo]*768 + 256 + h*32 + td*16 + hi*8);
        #pragma unroll
        for (int nt = 0; nt < 2; ++nt)
            #pragma unroll
            for (int td = 0; td < 2; ++td)
                qf[nt][td] = *(const bf16x8*)(qkv + (size_t)tok[nt*32 + lo]*768 + h*32 + td*16 + hi*8);

        f32x16 s[2][2];
        #pragma unroll
        for (int mt = 0; mt < 2; ++mt)
            #pragma unroll
            for (int nt = 0; nt < 2; ++nt) {
                f32x16 z;
                #pragma unroll
                for (int i = 0; i < 16; ++i) z[i] = 0.f;
                s[mt][nt] = z;
            }
        #pragma unroll
        for (int td = 0; td < 2; ++td)
            #pragma unroll
            for (int mt = 0; mt < 2; ++mt)
                #pragma unroll
                for (int nt = 0; nt < 2; ++nt)
                    s[mt][nt] = __builtin_amdgcn_mfma_f32_32x32x16_bf16(kf[mt][td], qf[nt][td], s[mt][nt], 0, 0, 0);

        asm volatile("s_waitcnt lgkmcnt(0)" ::: "memory");
        __builtin_amdgcn_sched_barrier(0);

        const float* bh = biasl + h*176;
        #pragma unroll
        for (int mt = 0; mt < 2; ++mt) {
            #pragma unroll
            for (int i = 0; i < 16; ++i) {
                int r = (i & 3) + 8*(i >> 2) + 4*hi;
                int k = mt*32 + r;
                bool valid = k < 49;
                int kb = valid ? k : 48;
                int ik = div7(kb), jk = kb - ik*7;
                int regk = 0;
                if (shift > 0) regk = reg3(wi*7 + ik)*3 + reg3(wj*7 + jk);
                #pragma unroll
                for (int nt = 0; nt < 2; ++nt) {
                    float v = s[mt][nt][i] * ATTN_SCALE
                            + bh[(iqv[nt] - ik + 6)*13 + (jqv[nt] - jk + 6)];
                    if (shift > 0 && regq[nt] != regk) v -= 100.0f;
                    if (!valid) v = -1e30f;
                    s[mt][nt][i] = v;
                }
            }
        }

        #pragma unroll
        for (int nt = 0; nt < 2; ++nt) {
            float mx = -1e30f;
            #pragma unroll
            for (int i = 0; i < 16; ++i) mx = fmaxf(mx, fmaxf(s[0][nt][i], s[1][nt][i]));
            mx = fmaxf(mx, __shfl_xor(mx, 32));
            float sum = 0.f;
            #pragma unroll
            for (int mt = 0; mt < 2; ++mt)
                #pragma unroll
                for (int i = 0; i < 16; ++i) {
                    float e = __expf(s[mt][nt][i] - mx);
                    s[mt][nt][i] = e;
                    sum += e;
                }
            sum += __shfl_xor(sum, 32);
            float inv = __builtin_amdgcn_rcpf(sum);

            u32 pk[2][8];
            #pragma unroll
            for (int mt = 0; mt < 2; ++mt)
                #pragma unroll
                for (int j = 0; j < 8; ++j)
                    pk[mt][j] = (u32)f2bf(s[mt][nt][2*j] * inv)
                              | ((u32)f2bf(s[mt][nt][2*j + 1] * inv) << 16);

            f32x16 o;
            #pragma unroll
            for (int i = 0; i < 16; ++i) o[i] = 0.f;
            #pragma unroll
            for (int kt = 0; kt < 4; ++kt) {
                const int mt = kt >> 1;
                const int base = (kt & 1) * 4;
                u32 a0 = pk[mt][base + 0], a1 = pk[mt][base + 1];
                u32 a2 = pk[mt][base + 2], a3 = pk[mt][base + 3];
                asm volatile("v_permlane32_swap_b32 %0, %1" : "+v"(a0), "+v"(a2));
                asm volatile("v_permlane32_swap_b32 %0, %1" : "+v"(a1), "+v"(a3));
                union { u32 u[4]; bf16x8 v; } pf;
                pf.u[0] = a0; pf.u[1] = a1; pf.u[2] = a2; pf.u[3] = a3;
                bf16x8 vb = *(const bf16x8*)(&Vt[h][lo*64 + ((kt*16 + hi*8) ^ ((lo & 7) << 3))]);
                o = __builtin_amdgcn_mfma_f32_32x32x16_bf16(pf.v, vb, o, 0, 0, 0);
            }

            #pragma unroll
            for (int i = 0; i < 16; ++i) {
                int q = nt*32 + (i & 3) + 8*(i >> 2) + 4*hi;
                if (q < 49)
                    outb[(size_t)tok[q]*256 + h*32 + lo] = f2bf(o[i]);
            }
        }
    }
}

// ---------------- host ----------------
extern "C" void kernel_launch(void* const* d_in, const int* in_sizes, int n_in,
                              void* d_out, int out_size, void* d_ws, size_t ws_size,
                              hipStream_t stream) {
    const float* x_in   = (const float*)d_in[0];
    const float* ln1_w  = (const float*)d_in[1];
    const float* ln1_b  = (const float*)d_in[2];
    const float* qkv_w  = (const float*)d_in[3];
    const float* qkv_b  = (const float*)d_in[4];
    const float* proj_w = (const float*)d_in[5];
    const float* proj_b = (const float*)d_in[6];
    const float* rpb    = (const float*)d_in[7];
    const float* ln2_w  = (const float*)d_in[8];
    const float* ln2_b  = (const float*)d_in[9];
    const float* mlp_w1 = (const float*)d_in[10];
    const float* mlp_b1 = (const float*)d_in[11];
    const float* mlp_w2 = (const float*)d_in[12];
    const float* mlp_b2 = (const float*)d_in[13];
    float* xout = (float*)d_out;

    char* p = (char*)d_ws;
    u16* wq = (u16*)p;  p += (size_t)2*768*256*2;
    u16* wp = (u16*)p;  p += (size_t)2*256*256*2;
    u16* w1 = (u16*)p;  p += (size_t)2*1024*256*2;
    u16* w2 = (u16*)p;  p += (size_t)2*256*1024*2;
    u16* buf_y   = (u16*)p; p += (size_t)T_TOK*256*2;
    u16* buf_big = (u16*)p;

    {
        int n;
        n = 2*768*256;  cvt_kernel<<<(n+255)/256, 256, 0, stream>>>(qkv_w,  wq, n);
        n = 2*256*256;  cvt_kernel<<<(n+255)/256, 256, 0, stream>>>(proj_w, wp, n);
        n = 2*1024*256; cvt_kernel<<<(n+255)/256, 256, 0, stream>>>(mlp_w1, w1, n);
        n = 2*256*1024; cvt_kernel<<<(n+255)/256, 256, 0, stream>>>(mlp_w2, w2, n);
    }

    for (int i = 0; i < 2; ++i) {
        const int shift = (i == 0) ? 0 : 3;
        const float* xcur = (i == 0) ? x_in : xout;

        ln_kernel<<<T_TOK/4, 256, 0, stream>>>(xcur, ln1_w + i*256, ln1_b + i*256, buf_y);
        gemm_kernel<0><<<784*6, 256, 0, stream>>>(
            buf_y, wq + (size_t)i*768*256, qkv_b + i*768, buf_big, nullptr, 768, 256, 6);
        attn_kernel<<<2048, 256, 0, stream>>>(buf_big, rpb + i*169*8, buf_y, shift);
        gemm_kernel<2><<<784*2, 256, 0, stream>>>(
            buf_y, wp + (size_t)i*256*256, proj_b + i*256, xout, xcur, 256, 256, 2);
        ln_kernel<<<T_TOK/4, 256, 0, stream>>>(xout, ln2_w + i*256, ln2_b + i*256, buf_y);
        gemm_kernel<1><<<784*8, 256, 0, stream>>>(
            buf_y, w1 + (size_t)i*1024*256, mlp_b1 + i*1024, buf_big, nullptr, 1024, 256, 8);
        gemm_kernel<2><<<784*2, 256, 0, stream>>>(
            buf_big, w2 + (size_t)i*256*1024, mlp_b2 + i*256, xout, xout, 256, 1024, 2);
    }
}

// Round 5
// 1000.622 us; speedup vs baseline: 1.3032x; 1.0510x over previous
//
#include <hip/hip_runtime.h>

typedef unsigned short u16;
typedef unsigned int u32;
typedef __attribute__((ext_vector_type(8))) short bf16x8;
typedef __attribute__((ext_vector_type(4))) float f32x4;
typedef __attribute__((ext_vector_type(16))) float f32x16;
typedef __attribute__((ext_vector_type(8))) unsigned short u16x8;
typedef const __attribute__((address_space(1))) void gvoid;
typedef __attribute__((address_space(3))) void svoid;

#define T_TOK 100352
#define CDIM 256
#define ATTN_SCALE 0.17677669529663687f

__device__ __forceinline__ u16 f2bf(float f) {
    u32 u = __float_as_uint(f);
    u32 r = (u + 0x7fffu + ((u >> 16) & 1u)) >> 16;
    return (u16)r;
}
__device__ __forceinline__ float bf2f(u16 h) {
    return __uint_as_float(((u32)h) << 16);
}
// tanh-form GELU: max abs dev from erf-form ~3e-4 (<< bf16 rounding of outputs)
__device__ __forceinline__ float gelu_f(float x) {
    float z = 0.7978845608028654f * (x + 0.044715f * x * x * x);
    float e = __expf(2.0f * z);
    float th = 1.0f - 2.0f * __builtin_amdgcn_rcpf(e + 1.0f);
    return 0.5f * x * (1.0f + th);
}
__device__ __forceinline__ int div7(int q) { return (q * 37) >> 8; }  // exact for 0..48
__device__ __forceinline__ int reg3(int r) { return r < 105 ? 0 : (r < 109 ? 1 : 2); }

// ---------------- fp32 -> bf16 weight conversion ----------------
__global__ void cvt_kernel(const float* __restrict__ in, u16* __restrict__ out, int n) {
    int i = blockIdx.x * 256 + threadIdx.x;
    if (i < n) out[i] = f2bf(in[i]);
}

// ---------------- LayerNorm (fp32 in, bf16 out) ----------------
__global__ __launch_bounds__(256) void ln_kernel(
    const float* __restrict__ X, const float* __restrict__ w,
    const float* __restrict__ b, u16* __restrict__ Y)
{
    int wid = threadIdx.x >> 6, l = threadIdx.x & 63;
    int t = blockIdx.x * 4 + wid;
    const float4 x4 = ((const float4*)(X + (size_t)t * CDIM))[l];
    float s  = x4.x + x4.y + x4.z + x4.w;
    float s2 = x4.x*x4.x + x4.y*x4.y + x4.z*x4.z + x4.w*x4.w;
    #pragma unroll
    for (int o = 32; o; o >>= 1) { s += __shfl_xor(s, o); s2 += __shfl_xor(s2, o); }
    float mean = s * (1.0f/256.0f);
    float var  = s2 * (1.0f/256.0f) - mean*mean;
    float rstd = rsqrtf(var + 1e-5f);
    float4 w4 = ((const float4*)w)[l];
    float4 b4 = ((const float4*)b)[l];
    ushort4 o4;
    o4.x = f2bf((x4.x - mean)*rstd*w4.x + b4.x);
    o4.y = f2bf((x4.y - mean)*rstd*w4.y + b4.y);
    o4.z = f2bf((x4.z - mean)*rstd*w4.z + b4.z);
    o4.w = f2bf((x4.w - mean)*rstd*w4.w + b4.w);
    ((ushort4*)(Y + (size_t)t * CDIM))[l] = o4;
}

// ---------------- bf16 MFMA GEMM:  out[M,N] = A[M,K] @ B[N,K]^T + bias ----------------
// 128x128 tile, BK=64, double-buffered LDS, 2-phase pipeline.
// Epilogue: wave-private LDS transpose -> coalesced 16B stores.
template<int EPI>
__global__ __launch_bounds__(256) void gemm_kernel(
    const u16* __restrict__ A, const u16* __restrict__ Bw,
    const float* __restrict__ bias, void* __restrict__ outp,
    const float* __restrict__ res, int N, int K, int nTn)
{
    __shared__ __align__(16) char lds_raw[69632];   // staging: 2x2x128x64 u16 = 64KB; epilogue: 4x17KB
    u16 (*lds)[2][128 * 64] = (u16(*)[2][128 * 64])lds_raw;
    const int tid = threadIdx.x;
    const int l = tid & 63;
    const int w = tid >> 6;
    const int wr = w >> 1, wc = w & 1;

    const int nBlocks = gridDim.x;
    const int cpx = nBlocks >> 3;
    const int lin = (blockIdx.x & 7) * cpx + (blockIdx.x >> 3);
    const int nT = lin % nTn;
    const int mT = lin / nTn;

    f32x4 acc[4][4];
    #pragma unroll
    for (int m = 0; m < 4; ++m)
        #pragma unroll
        for (int n = 0; n < 4; ++n) acc[m][n] = (f32x4){0.f,0.f,0.f,0.f};

    const int sr = tid >> 3;
    const int sg = tid & 7;

    #define STAGE(buf, kt)                                                              \
        {                                                                               \
            _Pragma("unroll")                                                           \
            for (int c = 0; c < 4; ++c) {                                               \
                int r = c*32 + sr;                                                      \
                int gsrc = sg ^ (r & 7);                                                \
                const u16* ga = A  + (size_t)(mT*128 + r) * K + (kt) + gsrc*8;          \
                const u16* gb = Bw + (size_t)(nT*128 + r) * K + (kt) + gsrc*8;          \
                u16* la = &lds[buf][0][(c*256 + w*64) * 8];                              \
                u16* lb = &lds[buf][1][(c*256 + w*64) * 8];                              \
                __builtin_amdgcn_global_load_lds((gvoid*)ga, (svoid*)la, 16, 0, 0);     \
                __builtin_amdgcn_global_load_lds((gvoid*)gb, (svoid*)lb, 16, 0, 0);     \
            }                                                                           \
        }

    const int nSteps = K >> 6;
    int cur = 0;

    STAGE(0, 0);
    asm volatile("s_waitcnt vmcnt(0)" ::: "memory");
    __builtin_amdgcn_s_barrier();
    asm volatile("" ::: "memory");

    const int lr = l & 15, gq = l >> 4;
    for (int t = 0; t < nSteps; ++t) {
        bf16x8 a[2][4], b[2][4];
        #pragma unroll
        for (int kk = 0; kk < 2; ++kk) {
            #pragma unroll
            for (int m = 0; m < 4; ++m) {
                int r = wr*64 + m*16 + lr;
                int g = kk*4 + gq;
                a[kk][m] = *(const bf16x8*)&lds[cur][0][r*64 + (g ^ (r & 7))*8];
            }
            #pragma unroll
            for (int n = 0; n < 4; ++n) {
                int r = wc*64 + n*16 + lr;
                int g = kk*4 + gq;
                b[kk][n] = *(const bf16x8*)&lds[cur][1][r*64 + (g ^ (r & 7))*8];
            }
        }
        if (t + 1 < nSteps) STAGE(cur ^ 1, (t + 1) * 64);

        __builtin_amdgcn_s_setprio(1);
        #pragma unroll
        for (int kk = 0; kk < 2; ++kk)
            #pragma unroll
            for (int m = 0; m < 4; ++m)
                #pragma unroll
                for (int n = 0; n < 4; ++n)
                    acc[m][n] = __builtin_amdgcn_mfma_f32_16x16x32_bf16(a[kk][m], b[kk][n], acc[m][n], 0, 0, 0);
        __builtin_amdgcn_s_setprio(0);

        asm volatile("s_waitcnt vmcnt(0)" ::: "memory");
        __builtin_amdgcn_s_barrier();
        asm volatile("" ::: "memory");
        cur ^= 1;
    }
    #undef STAGE

    // ---- epilogue: wave-private LDS transpose -> coalesced stores ----
    // (all waves are past the final barrier; each wave touches only its own region)
    if (EPI == 2) {
        // fp32 + residual, stride 68 floats (272B rows, 16B aligned, 4-bank stagger)
        float* epf = (float*)lds_raw + w * (64 * 68);
        #pragma unroll
        for (int m = 0; m < 4; ++m)
            #pragma unroll
            for (int n = 0; n < 4; ++n) {
                float bb = bias[nT*128 + wc*64 + n*16 + lr];
                #pragma unroll
                for (int j = 0; j < 4; ++j)
                    epf[(m*16 + gq*4 + j)*68 + n*16 + lr] = acc[m][n][j] + bb;
            }
        const int rr4 = l >> 4, cc4 = (l & 15) * 4;
        float* outf = (float*)outp;
        #pragma unroll
        for (int p = 0; p < 16; ++p) {
            float4 vv = *(const float4*)&epf[(p*4 + rr4)*68 + cc4];
            size_t grow = (size_t)(mT*128 + wr*64 + p*4 + rr4);
            size_t gcol = (size_t)(nT*128 + wc*64 + cc4);
            float4 rv = *(const float4*)(res + grow*N + gcol);
            float4 ov; ov.x = vv.x + rv.x; ov.y = vv.y + rv.y;
            ov.z = vv.z + rv.z; ov.w = vv.w + rv.w;
            *(float4*)(outf + grow*N + gcol) = ov;
        }
    } else {
        // bf16 out, stride 72 u16 (144B rows, 16B aligned)
        u16* ep = (u16*)lds_raw + w * (64 * 72);
        #pragma unroll
        for (int m = 0; m < 4; ++m)
            #pragma unroll
            for (int n = 0; n < 4; ++n) {
                float bb = bias[nT*128 + wc*64 + n*16 + lr];
                #pragma unroll
                for (int j = 0; j < 4; ++j) {
                    float v = acc[m][n][j] + bb;
                    if (EPI == 1) v = gelu_f(v);
                    ep[(m*16 + gq*4 + j)*72 + n*16 + lr] = f2bf(v);
                }
            }
        const int rr8 = l >> 3, cc8 = (l & 7) * 8;
        u16* outw = (u16*)outp;
        #pragma unroll
        for (int p = 0; p < 8; ++p) {
            u16x8 vv = *(const u16x8*)&ep[(p*8 + rr8)*72 + cc8];
            size_t grow = (size_t)(mT*128 + wr*64 + p*8 + rr8);
            size_t gcol = (size_t)(nT*128 + wc*64 + cc8);
            *(u16x8*)(outw + grow*N + gcol) = vv;
        }
    }
}

// ---------------- MFMA windowed attention, swapped-QK^T 32x32 ----------------
__global__ __launch_bounds__(256) void attn_kernel(
    const u16* __restrict__ qkv, const float* __restrict__ rpb,
    u16* __restrict__ outb, int shift)
{
    __shared__ u16 Vt[8][2048];       // head h: Vt[h][d*64 + (k ^ ((d&7)<<3))]
    __shared__ float biasl[8 * 176];
    __shared__ int tok[64];

    const int t = threadIdx.x;
    const int w = t >> 6;
    const int l = t & 63;
    const int lo = l & 31;
    const int hi = l >> 5;
    const int win = blockIdx.x;
    const int wj = win & 15, wi = (win >> 4) & 15, bb = win >> 8;

    if (t < 64) {
        int qq = t > 48 ? 48 : t;
        int i = div7(qq), j = qq - i*7;
        int rr = wi*7 + i + shift; if (rr >= 112) rr -= 112;
        int cc = wj*7 + j + shift; if (cc >= 112) cc -= 112;
        tok[t] = bb*12544 + rr*112 + cc;
    }
    for (int i2 = t; i2 < 1352; i2 += 256)
        biasl[(i2 & 7)*176 + (i2 >> 3)] = rpb[i2];
    __syncthreads();

    int iqv[2], jqv[2], regq[2];
    #pragma unroll
    for (int nt = 0; nt < 2; ++nt) {
        int q = nt*32 + lo; int qb = q > 48 ? 48 : q;
        int iq = div7(qb), jq = qb - iq*7;
        iqv[nt] = iq; jqv[nt] = jq;
        regq[nt] = 0;
        if (shift > 0) regq[nt] = reg3(wi*7 + iq)*3 + reg3(wj*7 + jq);
    }

    #pragma unroll 1
    for (int hh = 0; hh < 2; ++hh) {
        const int h = 2*w + hh;

        {
            u16x8 vreg[4];
            if (l < 49) {
                const u16x8* vs = (const u16x8*)(qkv + (size_t)tok[l]*768 + 512 + h*32);
                #pragma unroll
                for (int c4 = 0; c4 < 4; ++c4) vreg[c4] = vs[c4];
            } else {
                #pragma unroll
                for (int c4 = 0; c4 < 4; ++c4) vreg[c4] = (u16x8){0,0,0,0,0,0,0,0};
            }
            u16* vt = &Vt[h][0];
            #pragma unroll
            for (int c4 = 0; c4 < 4; ++c4)
                #pragma unroll
                for (int e = 0; e < 8; ++e)
                    vt[(c4*8 + e)*64 + (l ^ (e << 3))] = vreg[c4][e];
        }

        bf16x8 kf[2][2], qf[2][2];
        #pragma unroll
        for (int mt = 0; mt < 2; ++mt)
            #pragma unroll
            for (int td = 0; td < 2; ++td)
                kf[mt][td] = *(const bf16x8*)(qkv + (size_t)tok[mt*32 + lo]*768 + 256 + h*32 + td*16 + hi*8);
        #pragma unroll
        for (int nt = 0; nt < 2; ++nt)
            #pragma unroll
            for (int td = 0; td < 2; ++td)
                qf[nt][td] = *(const bf16x8*)(qkv + (size_t)tok[nt*32 + lo]*768 + h*32 + td*16 + hi*8);

        f32x16 s[2][2];
        #pragma unroll
        for (int mt = 0; mt < 2; ++mt)
            #pragma unroll
            for (int nt = 0; nt < 2; ++nt) {
                f32x16 z;
                #pragma unroll
                for (int i = 0; i < 16; ++i) z[i] = 0.f;
                s[mt][nt] = z;
            }
        #pragma unroll
        for (int td = 0; td < 2; ++td)
            #pragma unroll
            for (int mt = 0; mt < 2; ++mt)
                #pragma unroll
                for (int nt = 0; nt < 2; ++nt)
                    s[mt][nt] = __builtin_amdgcn_mfma_f32_32x32x16_bf16(kf[mt][td], qf[nt][td], s[mt][nt], 0, 0, 0);

        asm volatile("s_waitcnt lgkmcnt(0)" ::: "memory");
        __builtin_amdgcn_sched_barrier(0);

        const float* bh = biasl + h*176;
        #pragma unroll
        for (int mt = 0; mt < 2; ++mt) {
            #pragma unroll
            for (int i = 0; i < 16; ++i) {
                int r = (i & 3) + 8*(i >> 2) + 4*hi;
                int k = mt*32 + r;
                bool valid = k < 49;
                int kb = valid ? k : 48;
                int ik = div7(kb), jk = kb - ik*7;
                int regk = 0;
                if (shift > 0) regk = reg3(wi*7 + ik)*3 + reg3(wj*7 + jk);
                #pragma unroll
                for (int nt = 0; nt < 2; ++nt) {
                    float v = s[mt][nt][i] * ATTN_SCALE
                            + bh[(iqv[nt] - ik + 6)*13 + (jqv[nt] - jk + 6)];
                    if (shift > 0 && regq[nt] != regk) v -= 100.0f;
                    if (!valid) v = -1e30f;
                    s[mt][nt][i] = v;
                }
            }
        }

        #pragma unroll
        for (int nt = 0; nt < 2; ++nt) {
            float mx = -1e30f;
            #pragma unroll
            for (int i = 0; i < 16; ++i) mx = fmaxf(mx, fmaxf(s[0][nt][i], s[1][nt][i]));
            mx = fmaxf(mx, __shfl_xor(mx, 32));
            float sum = 0.f;
            #pragma unroll
            for (int mt = 0; mt < 2; ++mt)
                #pragma unroll
                for (int i = 0; i < 16; ++i) {
                    float e = __expf(s[mt][nt][i] - mx);
                    s[mt][nt][i] = e;
                    sum += e;
                }
            sum += __shfl_xor(sum, 32);
            float inv = __builtin_amdgcn_rcpf(sum);

            u32 pk[2][8];
            #pragma unroll
            for (int mt = 0; mt < 2; ++mt)
                #pragma unroll
                for (int j = 0; j < 8; ++j)
                    pk[mt][j] = (u32)f2bf(s[mt][nt][2*j] * inv)
                              | ((u32)f2bf(s[mt][nt][2*j + 1] * inv) << 16);

            f32x16 o;
            #pragma unroll
            for (int i = 0; i < 16; ++i) o[i] = 0.f;
            #pragma unroll
            for (int kt = 0; kt < 4; ++kt) {
                const int mt = kt >> 1;
                const int base = (kt & 1) * 4;
                u32 a0 = pk[mt][base + 0], a1 = pk[mt][base + 1];
                u32 a2 = pk[mt][base + 2], a3 = pk[mt][base + 3];
                asm volatile("v_permlane32_swap_b32 %0, %1" : "+v"(a0), "+v"(a2));
                asm volatile("v_permlane32_swap_b32 %0, %1" : "+v"(a1), "+v"(a3));
                union { u32 u[4]; bf16x8 v; } pf;
                pf.u[0] = a0; pf.u[1] = a1; pf.u[2] = a2; pf.u[3] = a3;
                bf16x8 vb = *(const bf16x8*)(&Vt[h][lo*64 + ((kt*16 + hi*8) ^ ((lo & 7) << 3))]);
                o = __builtin_amdgcn_mfma_f32_32x32x16_bf16(pf.v, vb, o, 0, 0, 0);
            }

            #pragma unroll
            for (int i = 0; i < 16; ++i) {
                int q = nt*32 + (i & 3) + 8*(i >> 2) + 4*hi;
                if (q < 49)
                    outb[(size_t)tok[q]*256 + h*32 + lo] = f2bf(o[i]);
            }
        }
    }
}

// ---------------- host ----------------
extern "C" void kernel_launch(void* const* d_in, const int* in_sizes, int n_in,
                              void* d_out, int out_size, void* d_ws, size_t ws_size,
                              hipStream_t stream) {
    const float* x_in   = (const float*)d_in[0];
    const float* ln1_w  = (const float*)d_in[1];
    const float* ln1_b  = (const float*)d_in[2];
    const float* qkv_w  = (const float*)d_in[3];
    const float* qkv_b  = (const float*)d_in[4];
    const float* proj_w = (const float*)d_in[5];
    const float* proj_b = (const float*)d_in[6];
    const float* rpb    = (const float*)d_in[7];
    const float* ln2_w  = (const float*)d_in[8];
    const float* ln2_b  = (const float*)d_in[9];
    const float* mlp_w1 = (const float*)d_in[10];
    const float* mlp_b1 = (const float*)d_in[11];
    const float* mlp_w2 = (const float*)d_in[12];
    const float* mlp_b2 = (const float*)d_in[13];
    float* xout = (float*)d_out;

    char* p = (char*)d_ws;
    u16* wq = (u16*)p;  p += (size_t)2*768*256*2;
    u16* wp = (u16*)p;  p += (size_t)2*256*256*2;
    u16* w1 = (u16*)p;  p += (size_t)2*1024*256*2;
    u16* w2 = (u16*)p;  p += (size_t)2*256*1024*2;
    u16* buf_y   = (u16*)p; p += (size_t)T_TOK*256*2;
    u16* buf_big = (u16*)p;

    {
        int n;
        n = 2*768*256;  cvt_kernel<<<(n+255)/256, 256, 0, stream>>>(qkv_w,  wq, n);
        n = 2*256*256;  cvt_kernel<<<(n+255)/256, 256, 0, stream>>>(proj_w, wp, n);
        n = 2*1024*256; cvt_kernel<<<(n+255)/256, 256, 0, stream>>>(mlp_w1, w1, n);
        n = 2*256*1024; cvt_kernel<<<(n+255)/256, 256, 0, stream>>>(mlp_w2, w2, n);
    }

    for (int i = 0; i < 2; ++i) {
        const int shift = (i == 0) ? 0 : 3;
        const float* xcur = (i == 0) ? x_in : xout;

        ln_kernel<<<T_TOK/4, 256, 0, stream>>>(xcur, ln1_w + i*256, ln1_b + i*256, buf_y);
        gemm_kernel<0><<<784*6, 256, 0, stream>>>(
            buf_y, wq + (size_t)i*768*256, qkv_b + i*768, buf_big, nullptr, 768, 256, 6);
        attn_kernel<<<2048, 256, 0, stream>>>(buf_big, rpb + i*169*8, buf_y, shift);
        gemm_kernel<2><<<784*2, 256, 0, stream>>>(
            buf_y, wp + (size_t)i*256*256, proj_b + i*256, xout, xcur, 256, 256, 2);
        ln_kernel<<<T_TOK/4, 256, 0, stream>>>(xout, ln2_w + i*256, ln2_b + i*256, buf_y);
        gemm_kernel<1><<<784*8, 256, 0, stream>>>(
            buf_y, w1 + (size_t)i*1024*256, mlp_b1 + i*1024, buf_big, nullptr, 1024, 256, 8);
        gemm_kernel<2><<<784*2, 256, 0, stream>>>(
            buf_big, w2 + (size_t)i*256*1024, mlp_b2 + i*256, xout, xout, 256, 1024, 2);
    }
}